// Round 8
// baseline (53140.125 us; speedup 1.0000x reference)
//
#include <hip/hip_runtime.h>
#include <hip/hip_cooperative_groups.h>
#include <stddef.h>
#include <math.h>

namespace cg = cooperative_groups;

static constexpr int B = 64, P = 196, ED = 2048, AD = 512, DD = 512, E = 300, V = 1000, T = 96, TD = 95;
static constexpr int KX = E + ED;      // 2348
static constexpr int KTOT = KX + DD;   // 2860
static constexpr int KSPLIT = 8;
static constexpr int KPER = 368;       // 23 tiles of 16; 8*368 = 2944 >= 2860
static constexpr int NG = 4 * DD;      // 2048
static constexpr int NC = 2560;        // combined att2(512) + fg(2048) col space

// d_out layout (all float32): predictions (B,TD,V), caps (B,T), decode_lengths (B),
// alphas (B,TD,P), sort_ind (B)
static constexpr size_t POFF   = 0;
static constexpr size_t CAPOFF = (size_t)B * TD * V;
static constexpr size_t DLOFF  = CAPOFF + (size_t)B * T;
static constexpr size_t AOFF   = DLOFF + B;
static constexpr size_t SOFF   = AOFF + (size_t)B * TD * P;

__device__ __forceinline__ float sigm(float x) { return 1.0f / (1.0f + expf(-x)); }

// ---------------------------------------------------------------------------
// K0: stable descending sort by length + gather caps + zero tail counters
// ---------------------------------------------------------------------------
__global__ __launch_bounds__(64) void k_sort(const int* __restrict__ lens,
                                             const int* __restrict__ caps_in,
                                             int* __restrict__ sidx,
                                             int* __restrict__ dlen,
                                             int* __restrict__ caps_s,
                                             unsigned int* __restrict__ cnt,
                                             float* __restrict__ out) {
    __shared__ int sl[B];
    __shared__ int ss[B];
    int i = threadIdx.x;
    sl[i] = lens[i];
    cnt[i] = 0u;
    cnt[i + 64] = 0u;
    __syncthreads();
    int li = sl[i];
    int r = 0;
    for (int j = 0; j < B; j++) {
        int lj = sl[j];
        r += (lj > li) || (lj == li && j < i);
    }
    ss[r] = i;
    sidx[r] = i;
    dlen[r] = li - 1;
    out[DLOFF + r] = (float)(li - 1);
    out[SOFF + r] = (float)i;
    __syncthreads();
    for (int idx = i; idx < B * T; idx += B) {
        int b = idx / T, tt = idx % T;
        int v = caps_in[ss[b] * T + tt];
        caps_s[idx] = v;
        out[CAPOFF + idx] = (float)v;
    }
}

// ---------------------------------------------------------------------------
// kE: precompute ALL timestep embedding gathers: embT[(t*E + k)*B + b]
// ---------------------------------------------------------------------------
__global__ __launch_bounds__(256) void k_emball(const float* __restrict__ emb,
                                                const int* __restrict__ caps_s,
                                                float* __restrict__ embT) {
    int t = blockIdx.x;
    int k0 = blockIdx.y * 60;
    for (int l = threadIdx.x; l < 60 * 64; l += 256) {
        int r = l >> 6, b = l & 63;
        int k = k0 + r;
        int cap = caps_s[b * T + t];
        embT[((size_t)t * E + k) * B + b] = emb[(size_t)cap * E + k];
    }
}

// ---------------------------------------------------------------------------
// K1: mean over P of sorted encoder_out -> mean_eo (B, ED)
// ---------------------------------------------------------------------------
__global__ __launch_bounds__(256) void k_mean(const float* __restrict__ eo,
                                              const int* __restrict__ sidx,
                                              float* __restrict__ mean_eo) {
    int b = blockIdx.y;
    int d = blockIdx.x * 256 + threadIdx.x;
    const float* base = eo + ((size_t)sidx[b] * P) * ED + d;
    float s = 0.f;
    for (int p = 0; p < P; p++) s += base[(size_t)p * ED];
    mean_eo[(size_t)b * ED + d] = s * (1.0f / (float)P);
}

// ---------------------------------------------------------------------------
// K2: h0/c0 init; c0 -> cb1 (c(-1) parity); h0 -> xT h-slot 1 (h(-1) parity)
// ---------------------------------------------------------------------------
__global__ __launch_bounds__(256) void k_init(const float* __restrict__ mean_eo,
                                              const float* __restrict__ Wh, const float* __restrict__ bh,
                                              const float* __restrict__ Wc, const float* __restrict__ bc,
                                              float* __restrict__ h0, float* __restrict__ c0,
                                              float* __restrict__ xT) {
    int idx = blockIdx.x * 256 + threadIdx.x;  // B*DD
    int b = idx >> 9, j = idx & 511;
    const float* m = mean_eo + (size_t)b * ED;
    float ah = bh[j], ac = bc[j];
    for (int k = 0; k < ED; k++) {
        float mv = m[k];
        ah += mv * Wh[(size_t)k * DD + j];
        ac += mv * Wc[(size_t)k * DD + j];
    }
    h0[idx] = ah;
    c0[idx] = ac;
    xT[(size_t)(KX + DD + j) * B + b] = ah;  // slot 1 = parity of h(t-1) for t=0
}

// ---------------------------------------------------------------------------
// K3: att1[m,n] = eo_sorted[m,:] @ W_enc_att[:,n] + b   (row-major, B*P x AD)
// ---------------------------------------------------------------------------
__global__ __launch_bounds__(256) void k_att1(const float* __restrict__ eo,
                                              const float* __restrict__ W,
                                              const float* __restrict__ bias,
                                              const int* __restrict__ sidx,
                                              float* __restrict__ att1) {
    int m0 = blockIdx.x * 64, n0 = blockIdx.y * 64;
    __shared__ float sA[16][68];
    __shared__ float sB[16][68];
    int tid = threadIdx.x;
    int tx = tid & 15, ty = tid >> 4;
    float acc[4][4] = {};

    int la_m = tid >> 2;
    int la_k = (tid & 3) * 4;
    int lb_k = tid >> 4;
    int lb_n = (tid & 15) * 4;

    int mA = m0 + la_m;
    int bA = mA / P, pA = mA % P;
    const float* arow = eo + ((size_t)sidx[bA] * P + pA) * ED;

    for (int k0 = 0; k0 < ED; k0 += 16) {
        float4 av = *(const float4*)(arow + k0 + la_k);
        sA[la_k + 0][la_m] = av.x;
        sA[la_k + 1][la_m] = av.y;
        sA[la_k + 2][la_m] = av.z;
        sA[la_k + 3][la_m] = av.w;
        float4 bv = *(const float4*)(W + (size_t)(k0 + lb_k) * AD + n0 + lb_n);
        *(float4*)&sB[lb_k][lb_n] = bv;
        __syncthreads();
#pragma unroll
        for (int kk = 0; kk < 16; kk++) {
            float4 a4 = *(const float4*)&sA[kk][ty * 4];
            float4 b4 = *(const float4*)&sB[kk][tx * 4];
            float av_[4] = {a4.x, a4.y, a4.z, a4.w};
            float bv_[4] = {b4.x, b4.y, b4.z, b4.w};
#pragma unroll
            for (int i = 0; i < 4; i++)
#pragma unroll
                for (int j = 0; j < 4; j++) acc[i][j] += av_[i] * bv_[j];
        }
        __syncthreads();
    }
#pragma unroll
    for (int i = 0; i < 4; i++) {
        int m = m0 + ty * 4 + i;
        int n = n0 + tx * 4;
        float4 o;
        o.x = acc[i][0] + bias[n + 0];
        o.y = acc[i][1] + bias[n + 1];
        o.z = acc[i][2] + bias[n + 2];
        o.w = acc[i][3] + bias[n + 3];
        *(float4*)(att1 + (size_t)m * AD + n) = o;
    }
}

// ---------------------------------------------------------------------------
// k_steps2: ONE cooperative kernel for the whole t-loop.
// 512 blocks x 256 threads (2 blocks/CU, 16 waves/CU). 4 grid.sync()/step.
// Phase bodies are the R7-proven kernels verbatim:
//   P1 = kA1 (320 blocks: 80 n-tiles x 4 ksplit, last-arrival bias/sigm tail)
//   P2 = kA2e (256 blocks: b x p-quarter e-compute)
//   P3 = kB   (512 blocks: (ch,b) redundant softmax + deep awe + xg)
//   P4 = kCD  (512 blocks: gates GEMM + last-arrival LSTM cell tail)
// LDS: phase-overlaid union, ~13.3 KB.
// ---------------------------------------------------------------------------
union SM {
    struct { float sH[2][16][68]; float sW[2][16][36]; unsigned int sOld; } p1;
    struct { float sa2[AD]; float swf[AD]; } p2;
    struct { float se[256]; float red[256]; float sal[200]; float part[4][260]; } p3;
    struct { float sW[2][16][36]; unsigned int sOld; } p4;
};

__global__ __launch_bounds__(256, 2) void k_steps2(
    const float* __restrict__ eo, const int* __restrict__ sidx,
    const int* __restrict__ dlen,
    const float* __restrict__ Wda, const float* __restrict__ Wfb,
    const float* __restrict__ bda, const float* __restrict__ bfb,
    const float* __restrict__ wfull, const float* __restrict__ bfull,
    const float* __restrict__ att1,
    const float* __restrict__ Wih, const float* __restrict__ Whh,
    const float* __restrict__ bih, const float* __restrict__ bhh,
    const float* __restrict__ h0, float* __restrict__ cb0, float* __restrict__ cb1,
    float* __restrict__ part1, unsigned int* __restrict__ cnt1,
    float* __restrict__ att2g, float* __restrict__ fg,
    float* __restrict__ eW, float* __restrict__ xT,
    float* __restrict__ gpart, unsigned int* __restrict__ cntCD,
    const float* __restrict__ embT, float* __restrict__ hseq,
    float* __restrict__ out)
{
    cg::grid_group grid = cg::this_grid();
    const int bid = blockIdx.x;
    const int tid = threadIdx.x;
    __shared__ SM sm;

#pragma unroll 1
    for (int t = 0; t < TD; t++) {
        const float* hprev = (t == 0) ? h0 : (hseq + (size_t)(t - 1) * B * DD);

        // =================== P1: att2 + fg GEMM (kA1) ===================
        if (bid < 320) {
            int nb = bid >> 2, ks = bid & 3;
            int n0 = nb * 32;
            bool is_att = (n0 < AD);
            const float* W = is_att ? Wda : Wfb;
            int ld = is_att ? AD : ED;
            int colb = is_att ? n0 : n0 - AD;
            int kbase = ks * 128;
            float acc[4][2] = {};
            int tb = tid & 15, tn = tid >> 4;
            int hb = tid >> 2, hq = tid & 3;
            int wk = tid >> 3, wn = (tid & 7) * 4;

            float4 hreg = *(const float4*)(hprev + (size_t)hb * DD + kbase + hq * 4);
            float4 wreg = make_float4(0.f, 0.f, 0.f, 0.f);
            if (tid < 128) wreg = *(const float4*)(W + (size_t)(kbase + wk) * ld + colb + wn);
            sm.p1.sH[0][hq * 4 + 0][hb] = hreg.x;
            sm.p1.sH[0][hq * 4 + 1][hb] = hreg.y;
            sm.p1.sH[0][hq * 4 + 2][hb] = hreg.z;
            sm.p1.sH[0][hq * 4 + 3][hb] = hreg.w;
            if (tid < 128) *(float4*)&sm.p1.sW[0][wk][wn] = wreg;
            __syncthreads();

            for (int tl = 0; tl < 8; tl++) {
                int cur = tl & 1, nxt = cur ^ 1;
                if (tl < 7) {
                    int k0 = kbase + (tl + 1) * 16;
                    hreg = *(const float4*)(hprev + (size_t)hb * DD + k0 + hq * 4);
                    if (tid < 128) wreg = *(const float4*)(W + (size_t)(k0 + wk) * ld + colb + wn);
                }
#pragma unroll
                for (int kk = 0; kk < 16; kk++) {
                    float4 hv = *(const float4*)&sm.p1.sH[cur][kk][tb * 4];
                    float w0 = sm.p1.sW[cur][kk][tn * 2 + 0];
                    float w1 = sm.p1.sW[cur][kk][tn * 2 + 1];
                    acc[0][0] += hv.x * w0; acc[0][1] += hv.x * w1;
                    acc[1][0] += hv.y * w0; acc[1][1] += hv.y * w1;
                    acc[2][0] += hv.z * w0; acc[2][1] += hv.z * w1;
                    acc[3][0] += hv.w * w0; acc[3][1] += hv.w * w1;
                }
                if (tl < 7) {
                    sm.p1.sH[nxt][hq * 4 + 0][hb] = hreg.x;
                    sm.p1.sH[nxt][hq * 4 + 1][hb] = hreg.y;
                    sm.p1.sH[nxt][hq * 4 + 2][hb] = hreg.z;
                    sm.p1.sH[nxt][hq * 4 + 3][hb] = hreg.w;
                    if (tid < 128) *(float4*)&sm.p1.sW[nxt][wk][wn] = wreg;
                }
                __syncthreads();
            }

#pragma unroll
            for (int i = 0; i < 4; i++)
#pragma unroll
                for (int j = 0; j < 2; j++) {
                    int b = tb * 4 + i, n = n0 + tn * 2 + j;
                    __hip_atomic_store(&part1[((size_t)ks * B + b) * NC + n], acc[i][j],
                                       __ATOMIC_RELAXED, __HIP_MEMORY_SCOPE_AGENT);
                }
            __syncthreads();
            if (tid == 0)
                sm.p1.sOld = __hip_atomic_fetch_add(&cnt1[nb], 1u, __ATOMIC_ACQ_REL, __HIP_MEMORY_SCOPE_AGENT);
            __syncthreads();
            if (sm.p1.sOld == 3u) {
                if (tid == 0)
                    __hip_atomic_store(&cnt1[nb], 0u, __ATOMIC_RELAXED, __HIP_MEMORY_SCOPE_AGENT);
#pragma unroll
                for (int rep = 0; rep < 8; rep++) {
                    int idx = rep * 256 + tid;
                    int b = idx >> 5, nn = idx & 31;
                    int n = n0 + nn;
                    float s = 0.f;
#pragma unroll
                    for (int k = 0; k < 4; k++)
                        s += __hip_atomic_load(&part1[((size_t)k * B + b) * NC + n],
                                               __ATOMIC_RELAXED, __HIP_MEMORY_SCOPE_AGENT);
                    if (is_att) att2g[(size_t)b * AD + n] = s + bda[n];
                    else {
                        int d = n - AD;
                        fg[(size_t)b * ED + d] = sigm(s + bfb[d]);
                    }
                }
            }
        }
        grid.sync();

        // =================== P2: e-compute (kA2e) ===================
        if (bid < 256) {
            int b = bid >> 2, ch = bid & 3;
            sm.p2.sa2[tid] = att2g[(size_t)b * AD + tid];
            sm.p2.sa2[tid + 256] = att2g[(size_t)b * AD + tid + 256];
            sm.p2.swf[tid] = wfull[tid];
            sm.p2.swf[tid + 256] = wfull[tid + 256];
            __syncthreads();

            int w = tid >> 6, lane = tid & 63;
            float bf0 = bfull[0];
            for (int pl = w; pl < 49; pl += 4) {
                int p = ch * 49 + pl;
                const float* row = att1 + ((size_t)b * P + p) * AD + lane * 8;
                float4 u0 = *(const float4*)row;
                float4 u1 = *(const float4*)(row + 4);
                float4 s0 = *(const float4*)&sm.p2.sa2[lane * 8];
                float4 s1 = *(const float4*)&sm.p2.sa2[lane * 8 + 4];
                float4 w0 = *(const float4*)&sm.p2.swf[lane * 8];
                float4 w1 = *(const float4*)&sm.p2.swf[lane * 8 + 4];
                float acc = fmaxf(u0.x + s0.x, 0.f) * w0.x + fmaxf(u0.y + s0.y, 0.f) * w0.y +
                            fmaxf(u0.z + s0.z, 0.f) * w0.z + fmaxf(u0.w + s0.w, 0.f) * w0.w +
                            fmaxf(u1.x + s1.x, 0.f) * w1.x + fmaxf(u1.y + s1.y, 0.f) * w1.y +
                            fmaxf(u1.z + s1.z, 0.f) * w1.z + fmaxf(u1.w + s1.w, 0.f) * w1.w;
#pragma unroll
                for (int mm = 32; mm >= 1; mm >>= 1) acc += __shfl_xor(acc, mm, 64);
                if (lane == 0) eW[(size_t)b * P + p] = acc + bf0;
            }
        }
        grid.sync();

        // =================== P3: softmax + awe + xg (kB) ===================
        {
            int b = bid >> 3, ch = bid & 7;
            sm.p3.se[tid] = (tid < P) ? eW[(size_t)b * P + tid] : -1e30f;
            __syncthreads();
            sm.p3.red[tid] = sm.p3.se[tid];
            __syncthreads();
            for (int s = 128; s > 0; s >>= 1) {
                if (tid < s) sm.p3.red[tid] = fmaxf(sm.p3.red[tid], sm.p3.red[tid + s]);
                __syncthreads();
            }
            float mx = sm.p3.red[0];
            __syncthreads();
            float ex = (tid < P) ? expf(sm.p3.se[tid] - mx) : 0.f;
            sm.p3.red[tid] = ex;
            __syncthreads();
            for (int s = 128; s > 0; s >>= 1) {
                if (tid < s) sm.p3.red[tid] += sm.p3.red[tid + s];
                __syncthreads();
            }
            float inv = 1.0f / sm.p3.red[0];
            if (tid < P) {
                float a = ex * inv;
                sm.p3.sal[tid] = a;
                if (ch == 0) {
                    float m = (dlen[b] > t) ? 1.f : 0.f;
                    out[AOFF + ((size_t)b * TD + t) * P + tid] = a * m;
                }
            }
            __syncthreads();

            int pg = tid >> 6, lane = tid & 63;
            int d = ch * 256 + lane * 4;
            const float* base = eo + ((size_t)sidx[b] * P) * ED + d;
            float ax = 0.f, ay = 0.f, az = 0.f, aw = 0.f;
#pragma unroll 7
            for (int i = 0; i < 49; i++) {
                int p = pg + i * 4;
                float4 v = *(const float4*)(base + (size_t)p * ED);
                float a = sm.p3.sal[p];
                ax += v.x * a; ay += v.y * a; az += v.z * a; aw += v.w * a;
            }
            sm.p3.part[pg][lane * 4 + 0] = ax;
            sm.p3.part[pg][lane * 4 + 1] = ay;
            sm.p3.part[pg][lane * 4 + 2] = az;
            sm.p3.part[pg][lane * 4 + 3] = aw;
            __syncthreads();
            if (tid < 64) {
                int d0 = ch * 256 + tid * 4;
                float4 g = *(const float4*)(fg + (size_t)b * ED + d0);
                float s0 = sm.p3.part[0][tid * 4 + 0] + sm.p3.part[1][tid * 4 + 0] + sm.p3.part[2][tid * 4 + 0] + sm.p3.part[3][tid * 4 + 0];
                float s1 = sm.p3.part[0][tid * 4 + 1] + sm.p3.part[1][tid * 4 + 1] + sm.p3.part[2][tid * 4 + 1] + sm.p3.part[3][tid * 4 + 1];
                float s2 = sm.p3.part[0][tid * 4 + 2] + sm.p3.part[1][tid * 4 + 2] + sm.p3.part[2][tid * 4 + 2] + sm.p3.part[3][tid * 4 + 2];
                float s3 = sm.p3.part[0][tid * 4 + 3] + sm.p3.part[1][tid * 4 + 3] + sm.p3.part[2][tid * 4 + 3] + sm.p3.part[3][tid * 4 + 3];
                xT[(size_t)(E + d0 + 0) * B + b] = g.x * s0;
                xT[(size_t)(E + d0 + 1) * B + b] = g.y * s1;
                xT[(size_t)(E + d0 + 2) * B + b] = g.z * s2;
                xT[(size_t)(E + d0 + 3) * B + b] = g.w * s3;
            }
        }
        grid.sync();

        // =================== P4: gates GEMM + cell tail (kCD) ===================
        {
            const float* embT_t = embT + (size_t)t * E * B;
            const float* xh_r = xT + (size_t)(KX + ((t + 1) & 1) * DD) * B;
            float*       xh_w = xT + (size_t)(KX + (t & 1) * DD) * B;
            const float* cread  = ((t + 1) & 1) ? cb1 : cb0;
            float*       cwrite = (t & 1) ? cb1 : cb0;

            int ks = bid >> 6, nb = bid & 63;
            int n0 = nb * 32;
            int tb = tid & 15, tn = tid >> 4;
            int wk = tid >> 3, wn = (tid & 7) * 4;
            float acc[4][2] = {};
            int kbase = ks * KPER;

            auto ldw = [&](int tile) -> float4 {
                int kg = kbase + tile * 16 + wk;
                float4 wv = make_float4(0.f, 0.f, 0.f, 0.f);
                if (kg < KX) wv = *(const float4*)&Wih[(size_t)kg * NG + n0 + wn];
                else if (kg < KTOT) wv = *(const float4*)&Whh[(size_t)(kg - KX) * NG + n0 + wn];
                return wv;
            };

            float4 wreg = make_float4(0.f, 0.f, 0.f, 0.f);
            if (tid < 128) {
                wreg = ldw(0);
                *(float4*)&sm.p4.sW[0][wk][wn] = wreg;
            }
            __syncthreads();

            for (int tile = 0; tile < 23; tile++) {
                int cur = tile & 1, nxt = cur ^ 1;
                if (tile < 22 && tid < 128) wreg = ldw(tile + 1);
#pragma unroll
                for (int kk = 0; kk < 16; kk++) {
                    int kg = kbase + tile * 16 + kk;
                    float4 xv = make_float4(0.f, 0.f, 0.f, 0.f);
                    if (kg < E) xv = *(const float4*)&embT_t[(size_t)kg * B + tb * 4];
                    else if (kg < KX) xv = *(const float4*)&xT[(size_t)kg * B + tb * 4];
                    else if (kg < KTOT) xv = *(const float4*)&xh_r[(size_t)(kg - KX) * B + tb * 4];
                    float w0 = sm.p4.sW[cur][kk][tn * 2 + 0];
                    float w1 = sm.p4.sW[cur][kk][tn * 2 + 1];
                    acc[0][0] += xv.x * w0; acc[0][1] += xv.x * w1;
                    acc[1][0] += xv.y * w0; acc[1][1] += xv.y * w1;
                    acc[2][0] += xv.z * w0; acc[2][1] += xv.z * w1;
                    acc[3][0] += xv.w * w0; acc[3][1] += xv.w * w1;
                }
                if (tile < 22 && tid < 128) *(float4*)&sm.p4.sW[nxt][wk][wn] = wreg;
                __syncthreads();
            }

#pragma unroll
            for (int i = 0; i < 4; i++)
#pragma unroll
                for (int j = 0; j < 2; j++) {
                    int b = tb * 4 + i, lc = tn * 2 + j;
                    __hip_atomic_store(&gpart[((size_t)ks * B + b) * NG + n0 + lc], acc[i][j],
                                       __ATOMIC_RELAXED, __HIP_MEMORY_SCOPE_AGENT);
                }
            __syncthreads();
            int jg = nb & 15;
            if (tid == 0)
                sm.p4.sOld = __hip_atomic_fetch_add(&cntCD[jg], 1u, __ATOMIC_ACQ_REL, __HIP_MEMORY_SCOPE_AGENT);
            __syncthreads();
            if (sm.p4.sOld == 31u) {
                if (tid == 0)
                    __hip_atomic_store(&cntCD[jg], 0u, __ATOMIC_RELAXED, __HIP_MEMORY_SCOPE_AGENT);
                const float* holds = (t == 0) ? h0 : (hseq + (size_t)(t - 1) * B * DD);
#pragma unroll
                for (int rep = 0; rep < 8; rep++) {
                    int idx = rep * 256 + tid;
                    int bb = idx >> 5;
                    int jj = idx & 31;
                    int j = jg * 32 + jj;
                    float g4[4];
#pragma unroll
                    for (int g = 0; g < 4; g++) {
                        float gv = bih[g * DD + j] + bhh[g * DD + j];
#pragma unroll
                        for (int s = 0; s < KSPLIT; s++)
                            gv += __hip_atomic_load(&gpart[((size_t)s * B + bb) * NG + g * 512 + j],
                                                    __ATOMIC_RELAXED, __HIP_MEMORY_SCOPE_AGENT);
                        g4[g] = gv;
                    }
                    float cold = cread[(size_t)bb * DD + j];
                    float hold = holds[(size_t)bb * DD + j];
                    float cnew = sigm(g4[1]) * cold + sigm(g4[0]) * tanhf(g4[2]);
                    float hnew = sigm(g4[3]) * tanhf(cnew);
                    bool m = dlen[bb] > t;
                    float h2 = m ? hnew : hold;
                    float c2 = m ? cnew : cold;
                    hseq[(size_t)t * B * DD + (size_t)bb * DD + j] = h2;
                    cwrite[(size_t)bb * DD + j] = c2;
                    xh_w[(size_t)j * B + bb] = h2;
                }
            }
        }
        grid.sync();
    }
}

// ---------------------------------------------------------------------------
// K4: batched preds GEMM: out[b,t,v] = mask * (hseq[t,b,:]@Wfc + bfc)
// ---------------------------------------------------------------------------
__global__ __launch_bounds__(256) void k_predsall(const float* __restrict__ hseq,
                                                  const float* __restrict__ Wfc,
                                                  const float* __restrict__ bfc,
                                                  const int* __restrict__ dlen,
                                                  float* __restrict__ out) {
    int t = blockIdx.x;
    int n0 = blockIdx.y * 64;
    int tid = threadIdx.x;
    int tx = tid & 15, ty = tid >> 4;
    __shared__ float sA[16][68];
    __shared__ float sB[16][68];
    float acc[4][4] = {};
    const float* A = hseq + (size_t)t * B * DD;

    for (int k0 = 0; k0 < DD; k0 += 16) {
        {
            int b = tid >> 2, q = tid & 3;
            float4 hv = *(const float4*)(A + (size_t)b * DD + k0 + q * 4);
            sA[q * 4 + 0][b] = hv.x;
            sA[q * 4 + 1][b] = hv.y;
            sA[q * 4 + 2][b] = hv.z;
            sA[q * 4 + 3][b] = hv.w;
        }
        {
            int kk = tid >> 4, nn = (tid & 15) * 4;
            int c = n0 + nn;
            const float* wrow = Wfc + (size_t)(k0 + kk) * V;
            float4 wv;
            if (c + 3 < V) wv = *(const float4*)(wrow + c);
            else {
                wv.x = (c + 0 < V) ? wrow[c + 0] : 0.f;
                wv.y = (c + 1 < V) ? wrow[c + 1] : 0.f;
                wv.z = (c + 2 < V) ? wrow[c + 2] : 0.f;
                wv.w = (c + 3 < V) ? wrow[c + 3] : 0.f;
            }
            *(float4*)&sB[kk][nn] = wv;
        }
        __syncthreads();
#pragma unroll
        for (int kk = 0; kk < 16; kk++) {
            float4 a4 = *(const float4*)&sA[kk][ty * 4];
            float4 b4 = *(const float4*)&sB[kk][tx * 4];
            float av_[4] = {a4.x, a4.y, a4.z, a4.w};
            float bv_[4] = {b4.x, b4.y, b4.z, b4.w};
#pragma unroll
            for (int i = 0; i < 4; i++)
#pragma unroll
                for (int j = 0; j < 4; j++) acc[i][j] += av_[i] * bv_[j];
        }
        __syncthreads();
    }
#pragma unroll
    for (int i = 0; i < 4; i++) {
        int b = ty * 4 + i;
        bool m = dlen[b] > t;
#pragma unroll
        for (int j = 0; j < 4; j++) {
            int n = n0 + tx * 4 + j;
            if (n < V)
                out[POFF + ((size_t)b * TD + t) * V + n] = m ? (acc[i][j] + bfc[n]) : 0.f;
        }
    }
}

// ---------------------------------------------------------------------------
extern "C" void kernel_launch(void* const* d_in, const int* in_sizes, int n_in,
                              void* d_out, int out_size, void* d_ws, size_t ws_size,
                              hipStream_t stream) {
    const float* eo    = (const float*)d_in[0];
    const int*   caps  = (const int*)d_in[1];
    const int*   lens  = (const int*)d_in[2];
    const float* emb   = (const float*)d_in[3];
    const float* Wea   = (const float*)d_in[4];
    const float* bea   = (const float*)d_in[5];
    const float* Wda   = (const float*)d_in[6];
    const float* bda   = (const float*)d_in[7];
    const float* wfull = (const float*)d_in[8];
    const float* bfull = (const float*)d_in[9];
    const float* Wih_  = (const float*)d_in[10];
    const float* bih_  = (const float*)d_in[11];
    const float* Wic   = (const float*)d_in[12];
    const float* bic   = (const float*)d_in[13];
    const float* Wfb   = (const float*)d_in[14];
    const float* bfb   = (const float*)d_in[15];
    const float* Wih   = (const float*)d_in[16];
    const float* bih   = (const float*)d_in[17];
    const float* Whh   = (const float*)d_in[18];
    const float* bhh   = (const float*)d_in[19];
    const float* Wfc   = (const float*)d_in[20];
    const float* bfc   = (const float*)d_in[21];
    float* out = (float*)d_out;

    char* w = (char*)d_ws;
    auto carve = [&](size_t bytes) -> void* {
        void* p = (void*)w;
        w += (bytes + 255) & ~(size_t)255;
        return p;
    };
    int* sidx      = (int*)carve(B * 4);
    int* dlen      = (int*)carve(B * 4);
    int* caps_s    = (int*)carve((size_t)B * T * 4);
    unsigned int* cnt = (unsigned int*)carve(128 * 4);
    float* mean_eo = (float*)carve((size_t)B * ED * 4);
    float* h0      = (float*)carve((size_t)B * DD * 4);
    float* cb0     = (float*)carve((size_t)B * DD * 4);
    float* cb1     = (float*)carve((size_t)B * DD * 4);
    float* att1    = (float*)carve((size_t)B * P * AD * 4);
    float* eWb     = (float*)carve((size_t)B * P * 4);
    float* att2g   = (float*)carve((size_t)B * AD * 4);
    float* fg      = (float*)carve((size_t)B * ED * 4);
    float* xT      = (float*)carve((size_t)(KTOT + DD) * B * 4);  // + extra h slot
    float* gpart   = (float*)carve((size_t)KSPLIT * B * NG * 4);
    float* part1   = (float*)carve((size_t)4 * B * NC * 4);
    float* hseq    = (float*)carve((size_t)TD * B * DD * 4);
    float* embT    = (float*)carve((size_t)TD * E * B * 4);
    unsigned int* cnt1  = cnt;        // 80 entries for P1
    unsigned int* cntCD = cnt + 96;   // 16 entries for P4

    k_sort<<<1, 64, 0, stream>>>(lens, caps, sidx, dlen, caps_s, cnt, out);
    k_emball<<<dim3(TD, 5), 256, 0, stream>>>(emb, caps_s, embT);
    k_mean<<<dim3(ED / 256, B), 256, 0, stream>>>(eo, sidx, mean_eo);
    k_init<<<(B * DD) / 256, 256, 0, stream>>>(mean_eo, Wih_, bih_, Wic, bic, h0, cb1, xT);
    k_att1<<<dim3((B * P) / 64, AD / 64), 256, 0, stream>>>(eo, Wea, bea, sidx, att1);

    void* kargs[] = {
        (void*)&eo, (void*)&sidx, (void*)&dlen,
        (void*)&Wda, (void*)&Wfb, (void*)&bda, (void*)&bfb,
        (void*)&wfull, (void*)&bfull, (void*)&att1,
        (void*)&Wih, (void*)&Whh, (void*)&bih, (void*)&bhh,
        (void*)&h0, (void*)&cb0, (void*)&cb1,
        (void*)&part1, (void*)&cnt1, (void*)&att2g, (void*)&fg,
        (void*)&eWb, (void*)&xT, (void*)&gpart, (void*)&cntCD,
        (void*)&embT, (void*)&hseq, (void*)&out
    };
    hipLaunchCooperativeKernel((void*)k_steps2, dim3(512), dim3(256), kargs, 0, stream);

    k_predsall<<<dim3(TD, 16), 256, 0, stream>>>(hseq, Wfc, bfc, dlen, out);
}